// Round 9
// baseline (392.988 us; speedup 1.0000x reference)
//
#include <hip/hip_runtime.h>

#define DM   1024
#define CUR  1024
#define TT   2048

typedef float  f32x4  __attribute__((ext_vector_type(4)));
typedef __bf16 bf16_t;
typedef __bf16 bf16x8 __attribute__((ext_vector_type(8)));
typedef __bf16 bf16x4 __attribute__((ext_vector_type(4)));
typedef short  s16x4  __attribute__((ext_vector_type(4)));

#define SCALE_A 0.18033688f   // 0.125 * log2(e): scores live in log2 domain

static __device__ __forceinline__ float exp2fast(float x) { return __builtin_amdgcn_exp2f(x); }

static __device__ __forceinline__ f32x4 mfma32(bf16x8 a, bf16x8 b, f32x4 c) {
  return __builtin_amdgcn_mfma_f32_16x16x32_bf16(a, b, c, 0, 0, 0);
}
static __device__ __forceinline__ f32x4 mfma16(bf16x4 a, bf16x4 b, f32x4 c) {
  return __builtin_amdgcn_mfma_f32_16x16x16bf16_1k(
      __builtin_bit_cast(s16x4, a), __builtin_bit_cast(s16x4, b), c, 0, 0, 0);
}
static __device__ __forceinline__ void gl_lds16(const bf16_t* g, bf16_t* l) {
  __builtin_amdgcn_global_load_lds(
      (const __attribute__((address_space(1))) void*)g,
      (__attribute__((address_space(3))) void*)l, 16, 0, 0);
}

// ---------------- fused prep: weight cvt + h concat cvt + pe fill ----------------
__global__ __launch_bounds__(256) void prep_kernel(const float* __restrict__ Wq,
                                                   const float* __restrict__ Wkv,
                                                   const float* __restrict__ Wfc,
                                                   const float* __restrict__ mem,
                                                   const float* __restrict__ x,
                                                   const float* __restrict__ pos,
                                                   bf16_t* __restrict__ wqb,
                                                   bf16_t* __restrict__ wkvb,
                                                   bf16_t* __restrict__ wfcb,
                                                   bf16_t* __restrict__ hb,
                                                   bf16_t* __restrict__ Bs) {
  int t = blockIdx.x * 256 + threadIdx.x;   // [0, 3M)
  if (t < (1 << 20)) {
    const float* src; bf16_t* dst; int off;
    if (t < 262144)      { src = Wq;  dst = wqb;  off = t; }
    else if (t < 786432) { src = Wkv; dst = wkvb; off = t - 262144; }
    else                 { src = Wfc; dst = wfcb; off = t - 786432; }
    f32x4 v = *(const f32x4*)(src + (size_t)off * 4);
    bf16x4 o;
    o[0] = (bf16_t)v[0]; o[1] = (bf16_t)v[1]; o[2] = (bf16_t)v[2]; o[3] = (bf16_t)v[3];
    *(bf16x4*)(dst + (size_t)off * 4) = o;
  } else if (t < (2 << 20)) {
    int th = t - (1 << 20);
    int idx = th << 2;
    int b   = idx >> 21;
    int rem = idx & ((1 << 21) - 1);
    int tt  = rem >> 10;
    int c   = rem & 1023;
    const float* s = (tt < 1024)
        ? (mem + ((size_t)b * 1024 + tt) * DM + c)
        : (x   + ((size_t)b * 1024 + (tt - 1024)) * DM + c);
    f32x4 v = *(const f32x4*)s;
    bf16x4 o;
    o[0] = (bf16_t)v[0]; o[1] = (bf16_t)v[1]; o[2] = (bf16_t)v[2]; o[3] = (bf16_t)v[3];
    *(bf16x4*)(hb + idx) = o;
  } else {
    int tp = t - (2 << 20);
    int d4 = (tp & 15) << 2;
    int j  = (tp >> 4) & 2047;
    int bh = tp >> 15;
    int h  = bh & 15;
    f32x4 v = *(const f32x4*)(pos + (size_t)j * DM + h * 64 + d4);
    bf16x4 o;
    o[0] = (bf16_t)v[0]; o[1] = (bf16_t)v[1]; o[2] = (bf16_t)v[2]; o[3] = (bf16_t)v[3];
    *(bf16x4*)(Bs + ((size_t)bh * TT + j) * 128 + 64 + d4) = o;
  }
}

// ---------------- LDS-staged GEMM core, double-buffered, XOR-swizzled ----------------
template<int WM>
__device__ __forceinline__ void gemm_core(const bf16_t* __restrict__ A,
                                          const bf16_t* __restrict__ B,
                                          int r0, int c0,
                                          bf16_t* At, bf16_t* Bt,
                                          f32x4 (&acc)[WM][4]) {
  const int ASZ = WM * 1024;
  const int BSZ = 4096;
  const int tid = threadIdx.x, w = tid >> 6, l = tid & 63;
  const int lm = l & 15, q = l >> 4;
  const int wrow = w >> 1, wcol = w & 1;
  const int gg  = (l & 3) ^ ((l >> 3) & 3);
  const int rsw = (lm >> 1) & 3;
  const bf16_t* gA = A + (size_t)(r0 + w * (WM / 2) * 16 + (l >> 2)) * 1024 + gg * 8;
  const bf16_t* gB = B + (size_t)(c0 + w * 32 + (l >> 2)) * 1024 + gg * 8;
  bf16_t* lA = At + w * (WM / 2) * 512;
  bf16_t* lB = Bt + w * 1024;
  const bf16_t* fA = At + (wrow * WM * 16 + lm) * 32;
  const bf16_t* fB = Bt + (wcol * 64 + lm) * 32;
#pragma unroll
  for (int t2 = 0; t2 < WM / 2; ++t2) gl_lds16(gA + (size_t)t2 * 16384, lA + t2 * 512);
#pragma unroll
  for (int t2 = 0; t2 < 2; ++t2)      gl_lds16(gB + (size_t)t2 * 16384, lB + t2 * 512);
  __syncthreads();
  int p = 0;
  for (int k0 = 0; k0 < 1024; k0 += 32) {
    int pn = p ^ 1;
    if (k0 < 992) {
#pragma unroll
      for (int t2 = 0; t2 < WM / 2; ++t2)
        gl_lds16(gA + (size_t)t2 * 16384 + k0 + 32, lA + pn * ASZ + t2 * 512);
#pragma unroll
      for (int t2 = 0; t2 < 2; ++t2)
        gl_lds16(gB + (size_t)t2 * 16384 + k0 + 32, lB + pn * BSZ + t2 * 512);
    }
    bf16x8 af[WM], bfm[4];
#pragma unroll
    for (int it = 0; it < WM; ++it)
      af[it] = *(const bf16x8*)(fA + p * ASZ + it * 512 + ((q ^ rsw) << 3));
#pragma unroll
    for (int jt = 0; jt < 4; ++jt)
      bfm[jt] = *(const bf16x8*)(fB + p * BSZ + jt * 512 + ((q ^ rsw) << 3));
#pragma unroll
    for (int it = 0; it < WM; ++it)
#pragma unroll
      for (int jt = 0; jt < 4; ++jt)
        acc[it][jt] = mfma32(af[it], bfm[jt], acc[it][jt]);
    __syncthreads();
    p = pn;
  }
}

// ---------------- K12: fused q-GEMM (k1) + kv-GEMM (k2) ----------------
__global__ __launch_bounds__(256) void k12_gemm(const bf16_t* __restrict__ hb,
                                                const bf16_t* __restrict__ Wqb,
                                                const bf16_t* __restrict__ Wkvb,
                                                const float* __restrict__ u,
                                                const float* __restrict__ v,
                                                bf16_t* __restrict__ As,
                                                bf16_t* __restrict__ Bs,
                                                bf16_t* __restrict__ vvT) {
  __shared__ union { struct { bf16_t At[8192]; bf16_t Bt[8192]; } m; float Tt[4][272]; } sm;
  const int tid = threadIdx.x, w = tid >> 6, l = tid & 63;
  const int lm = l & 15, q = l >> 4;
  const int wrow = w >> 1, wcol = w & 1;
  int blk = blockIdx.x;
  if (blk < 512) {
    int xcd = blk & 7, t = blk >> 3;
    int r0 = (t & 31) * 128;
    int c0 = (xcd * 2 + (t >> 5)) * 128;
    f32x4 acc[4][4] = {};
    gemm_core<4>(hb, Wkvb, r0, c0, sm.m.At, sm.m.Bt, acc);
    int b = r0 >> 11;
    if (c0 < 1024) {
      float* Tw = sm.Tt[w];
      int h = (c0 + wcol * 64) >> 6;
#pragma unroll
      for (int it = 0; it < 4; ++it) {
#pragma unroll
        for (int jt = 0; jt < 4; ++jt) {
#pragma unroll
          for (int r = 0; r < 4; ++r) Tw[(q * 4 + r) * 17 + lm] = acc[it][jt][r];
          __builtin_amdgcn_wave_barrier();
          int j = (r0 + wrow * 64 + it * 16 + lm) & 2047;
          int d0 = jt * 16 + q * 4;
          bf16x4 o;
#pragma unroll
          for (int e = 0; e < 4; ++e) o[e] = (bf16_t)Tw[lm * 17 + q * 4 + e];
          *(bf16x4*)(Bs + (((size_t)(b * 16 + h)) * TT + j) * 128 + d0) = o;
          __builtin_amdgcn_wave_barrier();
        }
      }
    } else {
#pragma unroll
      for (int it = 0; it < 4; ++it) {
#pragma unroll
        for (int jt = 0; jt < 4; ++jt) {
          int c2 = c0 + wcol * 64 + jt * 16 + lm - 1024;
          int h = c2 >> 6, d = c2 & 63;
          int j = (r0 + wrow * 64 + it * 16 + q * 4) & 2047;
          bf16x4 o;
#pragma unroll
          for (int r = 0; r < 4; ++r) o[r] = (bf16_t)acc[it][jt][r];
          *(bf16x4*)(vvT + (((size_t)(b * 16 + h)) * 64 + d) * TT + j) = o;
        }
      }
    }
  } else {
    int blk2 = blk - 512;
    int r0 = (blk2 >> 3) * 64, c0 = (blk2 & 7) * 128;
    int b = r0 >> 10;
    const bf16_t* Axv = hb + ((size_t)(b + 1) << 20);
    f32x4 acc[2][4] = {};
    gemm_core<2>(Axv, Wqb, r0, c0, sm.m.At, sm.m.Bt, acc);
    float* Tw = sm.Tt[w];
    int h = (c0 + wcol * 64) >> 6;
#pragma unroll
    for (int it = 0; it < 2; ++it) {
#pragma unroll
      for (int jt = 0; jt < 4; ++jt) {
#pragma unroll
        for (int r = 0; r < 4; ++r) Tw[(q * 4 + r) * 17 + lm] = acc[it][jt][r];
        __builtin_amdgcn_wave_barrier();
        int row = r0 + wrow * 32 + it * 16 + lm;
        int ii = row & 1023;
        int cbase = c0 + wcol * 64 + jt * 16 + q * 4;
        int d0 = cbase & 63;
        f32x4 u4 = *(const f32x4*)(u + cbase);
        f32x4 v4 = *(const f32x4*)(v + cbase);
        f32x4 tv;
#pragma unroll
        for (int e = 0; e < 4; ++e) tv[e] = Tw[lm * 17 + q * 4 + e];
        bf16x4 oc, op;
#pragma unroll
        for (int e = 0; e < 4; ++e) {
          oc[e] = (bf16_t)((tv[e] + u4[e]) * SCALE_A);
          op[e] = (bf16_t)((tv[e] + v4[e]) * SCALE_A);
        }
        *(bf16x4*)(As + (((size_t)(b * 16 + h)) * CUR + ii) * 128 + d0) = oc;
        if (b == 0) {
          if (ii >= 1)
            *(bf16x4*)(As + (((size_t)h) * CUR + (ii - 1)) * 128 + 64 + d0) = op;
          if (ii == 1023) {
            bf16x4 z = {};
            *(bf16x4*)(As + (((size_t)h) * CUR + 1023) * 128 + 64 + d0) = z;
          }
        } else {
          *(bf16x4*)(As + (((size_t)(16 + h)) * CUR + ii) * 128 + 64 + d0) = op;
        }
        __builtin_amdgcn_wave_barrier();
      }
    }
  }
}

// ---------------- K3: partial col-sums over i-chunk: Lp[ich][bh][j] = sum exp2(s) ----------------
__global__ __launch_bounds__(256) void k3_stats(const bf16_t* __restrict__ As,
                                                const bf16_t* __restrict__ Bs,
                                                float* __restrict__ Lp) {
  __shared__ bf16_t At[2 * 8192];
  const int tid = threadIdx.x, w = tid >> 6, l = tid & 63;
  const int lm = l & 15, q = l >> 4;
  const int gg  = (l & 3) ^ ((l >> 3) & 3);
  const int rsw = (lm >> 1) & 3;
  int blk = blockIdx.x;
  int xcd = blk & 7, t = blk >> 3;
  int jblk = t & 3, ich = (t >> 2) & 3, bh = xcd * 4 + (t >> 4);
  int j0 = jblk * 512 + w * 128;
  const bf16_t* bsrow = Bs + ((size_t)bh * TT + j0 + lm) * 128 + q * 8;
  bf16x8 bfr[8][4];
#pragma unroll
  for (int js = 0; js < 8; ++js)
#pragma unroll
    for (int kt = 0; kt < 4; ++kt)
      bfr[js][kt] = *(const bf16x8*)(bsrow + js * 2048 + kt * 32);
  const bf16_t* abase = As + (size_t)bh * CUR * 128 +
                        (size_t)(ich * 256 + (l >> 2)) * 128 + w * 32 + gg * 8;
  bf16_t* lA = At + w * 2048;
  const bf16_t* fA = At + lm * 32;
  float lacc[8] = {};
#pragma unroll
  for (int t2 = 0; t2 < 4; ++t2)
    gl_lds16(abase + (size_t)t2 * 16 * 128, lA + t2 * 512);
  __syncthreads();
  int p = 0;
  for (int ib = 0; ib < 4; ++ib) {
    int pn = p ^ 1;
    if (ib < 3) {
#pragma unroll
      for (int t2 = 0; t2 < 4; ++t2)
        gl_lds16(abase + (size_t)((ib + 1) * 64 + t2 * 16) * 128, lA + pn * 8192 + t2 * 512);
    }
#pragma unroll
    for (int isub = 0; isub < 4; ++isub) {
      bf16x8 af[4];
#pragma unroll
      for (int kt = 0; kt < 4; ++kt)
        af[kt] = *(const bf16x8*)(fA + p * 8192 + kt * 2048 + isub * 512 + ((q ^ rsw) << 3));
#pragma unroll
      for (int js = 0; js < 8; ++js) {
        f32x4 s = {};
#pragma unroll
        for (int kt = 0; kt < 4; ++kt)
          s = mfma32(af[kt], bfr[js][kt], s);
        lacc[js] += (exp2fast(s[0]) + exp2fast(s[1])) + (exp2fast(s[2]) + exp2fast(s[3]));
      }
    }
    __syncthreads();
    p = pn;
  }
#pragma unroll
  for (int js = 0; js < 8; ++js) {
#pragma unroll
    for (int off = 16; off <= 32; off <<= 1)
      lacc[js] += __shfl_xor(lacc[js], off, 64);
  }
  if (l < 16) {
    float* lp = Lp + (size_t)ich * 65536 + (size_t)bh * TT + j0;
#pragma unroll
    for (int js = 0; js < 8; ++js) lp[js * 16 + l] = lacc[js];
  }
}

// ---------------- vscale: vvT[bh][d][j] *= rcp(sum_ich Lp[ich][j]) (in place) ----------------
__global__ __launch_bounds__(256) void vscale(const float* __restrict__ Lp,
                                              bf16_t* __restrict__ vvT) {
  int bh = blockIdx.x >> 3, jc = blockIdx.x & 7;
  int tid = threadIdx.x;
  int jj = jc * 256 + (tid & 63) * 4;
  int dg = tid >> 6;
  const float* lp = Lp + (size_t)bh * TT + jj;
  f32x4 a0 = *(const f32x4*)lp;
  f32x4 a1 = *(const f32x4*)(lp + 65536);
  f32x4 a2 = *(const f32x4*)(lp + 131072);
  f32x4 a3 = *(const f32x4*)(lp + 196608);
  f32x4 rl;
#pragma unroll
  for (int e = 0; e < 4; ++e)
    rl[e] = __builtin_amdgcn_rcpf((a0[e] + a1[e]) + (a2[e] + a3[e]));
  bf16_t* vb = vvT + ((size_t)bh * 64 + dg * 16) * TT + jj;
#pragma unroll
  for (int dd = 0; dd < 16; ++dd) {
    bf16x4 vv = *(const bf16x4*)(vb + (size_t)dd * TT);
    bf16x4 o;
#pragma unroll
    for (int e = 0; e < 4; ++e) o[e] = (bf16_t)((float)vv[e] * rl[e]);
    *(bf16x4*)(vb + (size_t)dd * TT) = o;
  }
}

// ---------------- K4: partial[i,d] over 256-j chunk; 512-thread blocks, 8 waves ----------------
// grid 512 = 8 xcd x (2 iblk x 4 bh' x 8 jch). Waves 0-3 stage Bt k-slices; waves 4-7
// stage Vt. Each wave computes 64 i x 256 j. 2 blocks/CU -> 16 waves/CU.
__global__ __launch_bounds__(512, 4) void k4_attnv(const bf16_t* __restrict__ As,
                                                   const bf16_t* __restrict__ Bs,
                                                   const bf16_t* __restrict__ vvT,
                                                   bf16_t* __restrict__ Pp) {
  __shared__ union {
    struct { bf16_t Bt[2 * 8192]; bf16_t Vt[2 * 4096]; } m;
    float Tt[8][1088];
  } sm;
  int blk = blockIdx.x;
  int xcd = blk & 7, tb = blk >> 3;
  int iblk = tb & 1, pl = tb >> 1;       // pl: bh'(4) x jch(8)
  int bh = xcd * 4 + (pl >> 3), jch = pl & 7;
  int b = bh >> 4, h = bh & 15;
  int i0 = iblk * 512;
  int jbase = jch * 256;
  const int tid = threadIdx.x, w = tid >> 6, l = tid & 63;
  const int lm = l & 15, q = l >> 4;
  const int gg  = (l & 3) ^ ((l >> 3) & 3);
  const int rsw = (lm >> 1) & 3;
  // register i-frags: wave w covers i = i0 + w*64 .. +63
  const bf16_t* ar = As + (size_t)bh * CUR * 128 + (size_t)(i0 + w * 64 + lm) * 128 + q * 8;
  bf16x8 bi[4][4];
#pragma unroll
  for (int is = 0; is < 4; ++is)
#pragma unroll
    for (int kt = 0; kt < 4; ++kt)
      bi[is][kt] = *(const bf16x8*)(ar + is * 2048 + kt * 32);
  // staging assignments
  bool stageB = (w < 4);
  int ws = stageB ? w : (w - 4);
  const bf16_t* bbase = Bs + ((size_t)bh * TT + jbase) * 128 + (size_t)(l >> 2) * 128 + ws * 32 + gg * 8;
  bf16_t* lB = sm.m.Bt + ws * 2048;
  int inst0 = ws * 2, inst1 = ws * 2 + 1;
  const bf16_t* vsrc0 = vvT + ((size_t)bh * 64 + (inst0 & 3) * 16 + (l >> 2)) * TT + jbase +
                        (inst0 >> 2) * 32 + gg * 8;
  const bf16_t* vsrc1 = vvT + ((size_t)bh * 64 + (inst1 & 3) * 16 + (l >> 2)) * TT + jbase +
                        (inst1 >> 2) * 32 + gg * 8;
  bf16_t* vdst0 = sm.m.Vt + (inst0 >> 2) * 2048 + (inst0 & 3) * 512;
  bf16_t* vdst1 = sm.m.Vt + (inst1 >> 2) * 2048 + (inst1 & 3) * 512;
  f32x4 acc[4][4] = {};
  // prologue: stage jb=0 into buf 0
  if (stageB) {
#pragma unroll
    for (int t2 = 0; t2 < 4; ++t2)
      gl_lds16(bbase + (size_t)t2 * 16 * 128, lB + t2 * 512);
  } else {
    gl_lds16(vsrc0, vdst0);
    gl_lds16(vsrc1, vdst1);
  }
  __syncthreads();
  int p = 0;
  for (int jb = 0; jb < 4; ++jb) {
    int pn = p ^ 1;
    if (jb < 3) {
      if (stageB) {
        const bf16_t* bs2 = bbase + (size_t)(jb + 1) * 64 * 128;
#pragma unroll
        for (int t2 = 0; t2 < 4; ++t2)
          gl_lds16(bs2 + (size_t)t2 * 16 * 128, lB + pn * 8192 + t2 * 512);
      } else {
        gl_lds16(vsrc0 + (jb + 1) * 64, vdst0 + pn * 4096);
        gl_lds16(vsrc1 + (jb + 1) * 64, vdst1 + pn * 4096);
      }
    }
    const bf16_t* fB = sm.m.Bt + p * 8192 + lm * 32;
    const bf16_t* vf = sm.m.Vt + p * 4096 + lm * 32;
#pragma unroll
    for (int js = 0; js < 4; ++js) {
      bf16x8 af[4];
#pragma unroll
      for (int kt = 0; kt < 4; ++kt)
        af[kt] = *(const bf16x8*)(fB + kt * 2048 + js * 512 + ((q ^ rsw) << 3));
      f32x4 s[4] = {};
#pragma unroll
      for (int is = 0; is < 4; ++is)
#pragma unroll
        for (int kt = 0; kt < 4; ++kt)
          s[is] = mfma32(af[kt], bi[is][kt], s[is]);
      bf16x4 pp[4];
#pragma unroll
      for (int is = 0; is < 4; ++is)
#pragma unroll
        for (int e = 0; e < 4; ++e)
          pp[is][e] = (bf16_t)exp2fast(s[is][e]);
      int vg = ((js & 1) << 1) | (q >> 1);
      const bf16_t* vfa = vf + (js >> 1) * 2048 + ((vg ^ rsw) << 3) + ((q & 1) << 2);
#pragma unroll
      for (int dt = 0; dt < 4; ++dt) {
        bf16x4 a2 = *(const bf16x4*)(vfa + dt * 512);
#pragma unroll
        for (int is = 0; is < 4; ++is)
          acc[is][dt] = mfma16(a2, pp[is], acc[is][dt]);
      }
    }
    __syncthreads();
    p = pn;
  }
  // epilogue: per i-subtile transpose wT[64 d][16 i] -> rows, store bf16 partials
  float* Tw = sm.Tt[w];
  bf16_t* pout = Pp + ((size_t)jch << 21);
  int ir = l >> 2, dc = (l & 3) * 16;
#pragma unroll
  for (int is = 0; is < 4; ++is) {
#pragma unroll
    for (int dt = 0; dt < 4; ++dt) {
      f32x4 a = acc[is][dt];
#pragma unroll
      for (int r = 0; r < 4; ++r) Tw[(dt * 16 + q * 4 + r) * 17 + lm] = a[r];
    }
    __builtin_amdgcn_wave_barrier();
    int i = i0 + w * 64 + is * 16 + ir;
    bf16_t* orow = pout + ((size_t)(b * CUR + i)) * DM + h * 64 + dc;
#pragma unroll
    for (int e4 = 0; e4 < 4; ++e4) {
      bf16x4 o;
#pragma unroll
      for (int e = 0; e < 4; ++e) o[e] = (bf16_t)Tw[(dc + e4 * 4 + e) * 17 + ir];
      *(bf16x4*)(orow + e4 * 4) = o;
    }
    __builtin_amdgcn_wave_barrier();
  }
}

// ---------------- K4r: wbuf = bf16(sum of 8 bf16 partial chunks) ----------------
__global__ __launch_bounds__(256) void k4_reduce(const bf16_t* __restrict__ P,
                                                 bf16_t* __restrict__ wbuf) {
  int t = blockIdx.x * 256 + threadIdx.x;
  float s[4] = {0.f, 0.f, 0.f, 0.f};
#pragma unroll
  for (int c = 0; c < 8; ++c) {
    bf16x4 v = *(const bf16x4*)(P + ((size_t)c << 21) + (size_t)t * 4);
#pragma unroll
    for (int e = 0; e < 4; ++e) s[e] += (float)v[e];
  }
  bf16x4 o;
#pragma unroll
  for (int e = 0; e < 4; ++e) o[e] = (bf16_t)s[e];
  *(bf16x4*)(wbuf + (size_t)t * 4) = o;
}

// ---------------- K5: y = x + w @ Wfc^T + bfc (transposed epilogue) ----------------
__global__ __launch_bounds__(256) void k5_fc(const bf16_t* __restrict__ wb,
                                             const bf16_t* __restrict__ Wfcb,
                                             const float* __restrict__ x,
                                             const float* __restrict__ bfc,
                                             float* __restrict__ y) {
  __shared__ union { struct { bf16_t At[4096]; bf16_t Bt[8192]; } m; float Tt[4][272]; } sm;
  int blk = blockIdx.x;
  int r0 = (blk >> 3) * 64, c0 = (blk & 7) * 128;
  f32x4 acc[2][4] = {};
  gemm_core<2>(wb, Wfcb, r0, c0, sm.m.At, sm.m.Bt, acc);
  const int tid = threadIdx.x, w = tid >> 6, l = tid & 63;
  const int lm = l & 15, q = l >> 4;
  const int wrow = w >> 1, wcol = w & 1;
  float* Tw = sm.Tt[w];
#pragma unroll
  for (int it = 0; it < 2; ++it) {
#pragma unroll
    for (int jt = 0; jt < 4; ++jt) {
#pragma unroll
      for (int r = 0; r < 4; ++r) Tw[(q * 4 + r) * 17 + lm] = acc[it][jt][r];
      __builtin_amdgcn_wave_barrier();
      int row = r0 + wrow * 32 + it * 16 + lm;
      int cb = c0 + wcol * 64 + jt * 16 + q * 4;
      f32x4 xb4 = *(const f32x4*)(x + (size_t)row * DM + cb);
      f32x4 bf4 = *(const f32x4*)(bfc + cb);
      f32x4 o;
#pragma unroll
      for (int e = 0; e < 4; ++e) o[e] = Tw[lm * 17 + q * 4 + e] + xb4[e] + bf4[e];
      *(f32x4*)(y + (size_t)row * DM + cb) = o;
      __builtin_amdgcn_wave_barrier();
    }
  }
}

// ---------------- K6: LayerNorm ----------------
__global__ __launch_bounds__(256) void k6_ln(const float* __restrict__ y,
                                             const float* __restrict__ gamma,
                                             const float* __restrict__ beta,
                                             float* __restrict__ out) {
  int row = blockIdx.x, t = threadIdx.x;
  const float* yr = y + (size_t)row * DM;
  f32x4 v = *(const f32x4*)(yr + t * 4);
  float s = v[0] + v[1] + v[2] + v[3];
  float ss = v[0] * v[0] + v[1] * v[1] + v[2] * v[2] + v[3] * v[3];
#pragma unroll
  for (int off = 1; off < 64; off <<= 1) {
    s += __shfl_xor(s, off, 64);
    ss += __shfl_xor(ss, off, 64);
  }
  __shared__ float ps[4], pss[4];
  int wv = t >> 6, ln = t & 63;
  if (ln == 0) { ps[wv] = s; pss[wv] = ss; }
  __syncthreads();
  s = ps[0] + ps[1] + ps[2] + ps[3];
  ss = pss[0] + pss[1] + pss[2] + pss[3];
  float mu = s * (1.0f / DM);
  float var = ss * (1.0f / DM) - mu * mu;
  float rstd = rsqrtf(var + 1e-5f);
  f32x4 g = *(const f32x4*)(gamma + t * 4);
  f32x4 bb = *(const f32x4*)(beta + t * 4);
  f32x4 o;
#pragma unroll
  for (int e = 0; e < 4; ++e) o[e] = (v[e] - mu) * rstd * g[e] + bb[e];
  *(f32x4*)(out + (size_t)row * DM + t * 4) = o;
}

// ---------------- launch ----------------
extern "C" void kernel_launch(void* const* d_in, const int* in_sizes, int n_in,
                              void* d_out, int out_size, void* d_ws, size_t ws_size,
                              hipStream_t stream) {
  const float* x    = (const float*)d_in[0];
  const float* pos  = (const float*)d_in[1];
  const float* u    = (const float*)d_in[2];
  const float* v    = (const float*)d_in[3];
  const float* mem  = (const float*)d_in[5];
  const float* Wq   = (const float*)d_in[6];
  const float* Wkv  = (const float*)d_in[7];
  const float* Wfc  = (const float*)d_in[8];
  const float* bfc  = (const float*)d_in[9];
  const float* gam  = (const float*)d_in[10];
  const float* bet  = (const float*)d_in[11];
  float* out = (float*)d_out;

  char* ws = (char*)d_ws;
  const size_t MB = 1ull << 20;
  bf16_t* hb   = (bf16_t*)(ws);              // 0-8    (prep -> k12)
  bf16_t* wqb  = (bf16_t*)(ws + 8 * MB);     // 8-10   (prep -> k12)
  bf16_t* wkvb = (bf16_t*)(ws + 10 * MB);    // 10-14  (prep -> k12)
  bf16_t* As   = (bf16_t*)(ws + 14 * MB);    // 14-22  (k12 -> k4)
  bf16_t* Bs   = (bf16_t*)(ws + 22 * MB);    // 22-38  (prep/k12 -> k4)
  bf16_t* vvT  = (bf16_t*)(ws + 38 * MB);    // 38-46  (k12 -> vscale -> k4)
  bf16_t* wfcb = (bf16_t*)(ws + 46 * MB);    // 46-48  (prep -> k5)
  float*  Lp   = (float*) (ws + 48 * MB);    // 1 MB   (k3 -> vscale), 4 slices
  bf16_t* Pp   = (bf16_t*)(ws + 49 * MB);    // 49-81  (k4 -> k4r), 8 x 4 MB
  bf16_t* wbuf = (bf16_t*)(ws);              // 0-4    (k4r -> k5, hb dead)
  float*  y    = (float*) (ws + 4 * MB);     // 4-12   (k5 -> k6)

  prep_kernel<<<12288, 256, 0, stream>>>(Wq, Wkv, Wfc, mem, x, pos,
                                         wqb, wkvb, wfcb, hb, Bs);
  k12_gemm<<<768, 256, 0, stream>>>(hb, wqb, wkvb, u, v, As, Bs, vvT);

  k3_stats<<<512, 256, 0, stream>>>(As, Bs, Lp);
  vscale<<<256, 256, 0, stream>>>(Lp, vvT);
  k4_attnv<<<512, 512, 0, stream>>>(As, Bs, vvT, Pp);
  k4_reduce<<<2048, 256, 0, stream>>>(Pp, wbuf);

  k5_fc<<<256, 256, 0, stream>>>(wbuf, wfcb, x, bfc, y);
  k6_ln<<<2048, 256, 0, stream>>>(y, gam, bet, out);
}

// Round 10
// 239.406 us; speedup vs baseline: 1.6415x; 1.6415x over previous
//
#include <hip/hip_runtime.h>

#define DM   1024
#define CUR  1024
#define TT   2048

typedef float  f32x4  __attribute__((ext_vector_type(4)));
typedef __bf16 bf16_t;
typedef __bf16 bf16x8 __attribute__((ext_vector_type(8)));
typedef __bf16 bf16x4 __attribute__((ext_vector_type(4)));
typedef short  s16x4  __attribute__((ext_vector_type(4)));

#define SCALE_A 0.18033688f   // 0.125 * log2(e): scores live in log2 domain

static __device__ __forceinline__ float exp2fast(float x) { return __builtin_amdgcn_exp2f(x); }

static __device__ __forceinline__ f32x4 mfma32(bf16x8 a, bf16x8 b, f32x4 c) {
  return __builtin_amdgcn_mfma_f32_16x16x32_bf16(a, b, c, 0, 0, 0);
}
static __device__ __forceinline__ f32x4 mfma16(bf16x4 a, bf16x4 b, f32x4 c) {
  return __builtin_amdgcn_mfma_f32_16x16x16bf16_1k(
      __builtin_bit_cast(s16x4, a), __builtin_bit_cast(s16x4, b), c, 0, 0, 0);
}
static __device__ __forceinline__ void gl_lds16(const bf16_t* g, bf16_t* l) {
  __builtin_amdgcn_global_load_lds(
      (const __attribute__((address_space(1))) void*)g,
      (__attribute__((address_space(3))) void*)l, 16, 0, 0);
}

// ---------------- fused prep: weight cvt + h concat cvt + pe fill ----------------
__global__ __launch_bounds__(256) void prep_kernel(const float* __restrict__ Wq,
                                                   const float* __restrict__ Wkv,
                                                   const float* __restrict__ Wfc,
                                                   const float* __restrict__ mem,
                                                   const float* __restrict__ x,
                                                   const float* __restrict__ pos,
                                                   bf16_t* __restrict__ wqb,
                                                   bf16_t* __restrict__ wkvb,
                                                   bf16_t* __restrict__ wfcb,
                                                   bf16_t* __restrict__ hb,
                                                   bf16_t* __restrict__ Bs) {
  int t = blockIdx.x * 256 + threadIdx.x;   // [0, 3M)
  if (t < (1 << 20)) {
    const float* src; bf16_t* dst; int off;
    if (t < 262144)      { src = Wq;  dst = wqb;  off = t; }
    else if (t < 786432) { src = Wkv; dst = wkvb; off = t - 262144; }
    else                 { src = Wfc; dst = wfcb; off = t - 786432; }
    f32x4 v = *(const f32x4*)(src + (size_t)off * 4);
    bf16x4 o;
    o[0] = (bf16_t)v[0]; o[1] = (bf16_t)v[1]; o[2] = (bf16_t)v[2]; o[3] = (bf16_t)v[3];
    *(bf16x4*)(dst + (size_t)off * 4) = o;
  } else if (t < (2 << 20)) {
    int th = t - (1 << 20);
    int idx = th << 2;
    int b   = idx >> 21;
    int rem = idx & ((1 << 21) - 1);
    int tt  = rem >> 10;
    int c   = rem & 1023;
    const float* s = (tt < 1024)
        ? (mem + ((size_t)b * 1024 + tt) * DM + c)
        : (x   + ((size_t)b * 1024 + (tt - 1024)) * DM + c);
    f32x4 v = *(const f32x4*)s;
    bf16x4 o;
    o[0] = (bf16_t)v[0]; o[1] = (bf16_t)v[1]; o[2] = (bf16_t)v[2]; o[3] = (bf16_t)v[3];
    *(bf16x4*)(hb + idx) = o;
  } else {
    int tp = t - (2 << 20);
    int d4 = (tp & 15) << 2;
    int j  = (tp >> 4) & 2047;
    int bh = tp >> 15;
    int h  = bh & 15;
    f32x4 v = *(const f32x4*)(pos + (size_t)j * DM + h * 64 + d4);
    bf16x4 o;
    o[0] = (bf16_t)v[0]; o[1] = (bf16_t)v[1]; o[2] = (bf16_t)v[2]; o[3] = (bf16_t)v[3];
    *(bf16x4*)(Bs + ((size_t)bh * TT + j) * 128 + 64 + d4) = o;
  }
}

// ---------------- LDS-staged GEMM core, double-buffered, XOR-swizzled ----------------
template<int WM>
__device__ __forceinline__ void gemm_core(const bf16_t* __restrict__ A,
                                          const bf16_t* __restrict__ B,
                                          int r0, int c0,
                                          bf16_t* At, bf16_t* Bt,
                                          f32x4 (&acc)[WM][4]) {
  const int ASZ = WM * 1024;
  const int BSZ = 4096;
  const int tid = threadIdx.x, w = tid >> 6, l = tid & 63;
  const int lm = l & 15, q = l >> 4;
  const int wrow = w >> 1, wcol = w & 1;
  const int gg  = (l & 3) ^ ((l >> 3) & 3);
  const int rsw = (lm >> 1) & 3;
  const bf16_t* gA = A + (size_t)(r0 + w * (WM / 2) * 16 + (l >> 2)) * 1024 + gg * 8;
  const bf16_t* gB = B + (size_t)(c0 + w * 32 + (l >> 2)) * 1024 + gg * 8;
  bf16_t* lA = At + w * (WM / 2) * 512;
  bf16_t* lB = Bt + w * 1024;
  const bf16_t* fA = At + (wrow * WM * 16 + lm) * 32;
  const bf16_t* fB = Bt + (wcol * 64 + lm) * 32;
#pragma unroll
  for (int t2 = 0; t2 < WM / 2; ++t2) gl_lds16(gA + (size_t)t2 * 16384, lA + t2 * 512);
#pragma unroll
  for (int t2 = 0; t2 < 2; ++t2)      gl_lds16(gB + (size_t)t2 * 16384, lB + t2 * 512);
  __syncthreads();
  int p = 0;
  for (int k0 = 0; k0 < 1024; k0 += 32) {
    int pn = p ^ 1;
    if (k0 < 992) {
#pragma unroll
      for (int t2 = 0; t2 < WM / 2; ++t2)
        gl_lds16(gA + (size_t)t2 * 16384 + k0 + 32, lA + pn * ASZ + t2 * 512);
#pragma unroll
      for (int t2 = 0; t2 < 2; ++t2)
        gl_lds16(gB + (size_t)t2 * 16384 + k0 + 32, lB + pn * BSZ + t2 * 512);
    }
    bf16x8 af[WM], bfm[4];
#pragma unroll
    for (int it = 0; it < WM; ++it)
      af[it] = *(const bf16x8*)(fA + p * ASZ + it * 512 + ((q ^ rsw) << 3));
#pragma unroll
    for (int jt = 0; jt < 4; ++jt)
      bfm[jt] = *(const bf16x8*)(fB + p * BSZ + jt * 512 + ((q ^ rsw) << 3));
#pragma unroll
    for (int it = 0; it < WM; ++it)
#pragma unroll
      for (int jt = 0; jt < 4; ++jt)
        acc[it][jt] = mfma32(af[it], bfm[jt], acc[it][jt]);
    __syncthreads();
    p = pn;
  }
}

// ---------------- K12: fused q-GEMM (k1) + kv-GEMM (k2) ----------------
__global__ __launch_bounds__(256) void k12_gemm(const bf16_t* __restrict__ hb,
                                                const bf16_t* __restrict__ Wqb,
                                                const bf16_t* __restrict__ Wkvb,
                                                const float* __restrict__ u,
                                                const float* __restrict__ v,
                                                bf16_t* __restrict__ As,
                                                bf16_t* __restrict__ Bs,
                                                bf16_t* __restrict__ vvT) {
  __shared__ union { struct { bf16_t At[8192]; bf16_t Bt[8192]; } m; float Tt[4][272]; } sm;
  const int tid = threadIdx.x, w = tid >> 6, l = tid & 63;
  const int lm = l & 15, q = l >> 4;
  const int wrow = w >> 1, wcol = w & 1;
  int blk = blockIdx.x;
  if (blk < 512) {
    int xcd = blk & 7, t = blk >> 3;
    int r0 = (t & 31) * 128;
    int c0 = (xcd * 2 + (t >> 5)) * 128;
    f32x4 acc[4][4] = {};
    gemm_core<4>(hb, Wkvb, r0, c0, sm.m.At, sm.m.Bt, acc);
    int b = r0 >> 11;
    if (c0 < 1024) {
      float* Tw = sm.Tt[w];
      int h = (c0 + wcol * 64) >> 6;
#pragma unroll
      for (int it = 0; it < 4; ++it) {
#pragma unroll
        for (int jt = 0; jt < 4; ++jt) {
#pragma unroll
          for (int r = 0; r < 4; ++r) Tw[(q * 4 + r) * 17 + lm] = acc[it][jt][r];
          __builtin_amdgcn_wave_barrier();
          int j = (r0 + wrow * 64 + it * 16 + lm) & 2047;
          int d0 = jt * 16 + q * 4;
          bf16x4 o;
#pragma unroll
          for (int e = 0; e < 4; ++e) o[e] = (bf16_t)Tw[lm * 17 + q * 4 + e];
          *(bf16x4*)(Bs + (((size_t)(b * 16 + h)) * TT + j) * 128 + d0) = o;
          __builtin_amdgcn_wave_barrier();
        }
      }
    } else {
#pragma unroll
      for (int it = 0; it < 4; ++it) {
#pragma unroll
        for (int jt = 0; jt < 4; ++jt) {
          int c2 = c0 + wcol * 64 + jt * 16 + lm - 1024;
          int h = c2 >> 6, d = c2 & 63;
          int j = (r0 + wrow * 64 + it * 16 + q * 4) & 2047;
          bf16x4 o;
#pragma unroll
          for (int r = 0; r < 4; ++r) o[r] = (bf16_t)acc[it][jt][r];
          *(bf16x4*)(vvT + (((size_t)(b * 16 + h)) * 64 + d) * TT + j) = o;
        }
      }
    }
  } else {
    int blk2 = blk - 512;
    int r0 = (blk2 >> 3) * 64, c0 = (blk2 & 7) * 128;
    int b = r0 >> 10;
    const bf16_t* Axv = hb + ((size_t)(b + 1) << 20);
    f32x4 acc[2][4] = {};
    gemm_core<2>(Axv, Wqb, r0, c0, sm.m.At, sm.m.Bt, acc);
    float* Tw = sm.Tt[w];
    int h = (c0 + wcol * 64) >> 6;
#pragma unroll
    for (int it = 0; it < 2; ++it) {
#pragma unroll
      for (int jt = 0; jt < 4; ++jt) {
#pragma unroll
        for (int r = 0; r < 4; ++r) Tw[(q * 4 + r) * 17 + lm] = acc[it][jt][r];
        __builtin_amdgcn_wave_barrier();
        int row = r0 + wrow * 32 + it * 16 + lm;
        int ii = row & 1023;
        int cbase = c0 + wcol * 64 + jt * 16 + q * 4;
        int d0 = cbase & 63;
        f32x4 u4 = *(const f32x4*)(u + cbase);
        f32x4 v4 = *(const f32x4*)(v + cbase);
        f32x4 tv;
#pragma unroll
        for (int e = 0; e < 4; ++e) tv[e] = Tw[lm * 17 + q * 4 + e];
        bf16x4 oc, op;
#pragma unroll
        for (int e = 0; e < 4; ++e) {
          oc[e] = (bf16_t)((tv[e] + u4[e]) * SCALE_A);
          op[e] = (bf16_t)((tv[e] + v4[e]) * SCALE_A);
        }
        *(bf16x4*)(As + (((size_t)(b * 16 + h)) * CUR + ii) * 128 + d0) = oc;
        if (b == 0) {
          if (ii >= 1)
            *(bf16x4*)(As + (((size_t)h) * CUR + (ii - 1)) * 128 + 64 + d0) = op;
          if (ii == 1023) {
            bf16x4 z = {};
            *(bf16x4*)(As + (((size_t)h) * CUR + 1023) * 128 + 64 + d0) = z;
          }
        } else {
          *(bf16x4*)(As + (((size_t)(16 + h)) * CUR + ii) * 128 + 64 + d0) = op;
        }
        __builtin_amdgcn_wave_barrier();
      }
    }
  }
}

// ---------------- K3: partial col-sums over i-chunk: Lp[ich][bh][j] = sum exp2(s) ----------------
__global__ __launch_bounds__(256) void k3_stats(const bf16_t* __restrict__ As,
                                                const bf16_t* __restrict__ Bs,
                                                float* __restrict__ Lp) {
  __shared__ bf16_t At[2 * 8192];
  const int tid = threadIdx.x, w = tid >> 6, l = tid & 63;
  const int lm = l & 15, q = l >> 4;
  const int gg  = (l & 3) ^ ((l >> 3) & 3);
  const int rsw = (lm >> 1) & 3;
  int blk = blockIdx.x;
  int xcd = blk & 7, t = blk >> 3;
  int jblk = t & 3, ich = (t >> 2) & 3, bh = xcd * 4 + (t >> 4);
  int j0 = jblk * 512 + w * 128;
  const bf16_t* bsrow = Bs + ((size_t)bh * TT + j0 + lm) * 128 + q * 8;
  bf16x8 bfr[8][4];
#pragma unroll
  for (int js = 0; js < 8; ++js)
#pragma unroll
    for (int kt = 0; kt < 4; ++kt)
      bfr[js][kt] = *(const bf16x8*)(bsrow + js * 2048 + kt * 32);
  const bf16_t* abase = As + (size_t)bh * CUR * 128 +
                        (size_t)(ich * 256 + (l >> 2)) * 128 + w * 32 + gg * 8;
  bf16_t* lA = At + w * 2048;
  const bf16_t* fA = At + lm * 32;
  float lacc[8] = {};
#pragma unroll
  for (int t2 = 0; t2 < 4; ++t2)
    gl_lds16(abase + (size_t)t2 * 16 * 128, lA + t2 * 512);
  __syncthreads();
  int p = 0;
  for (int ib = 0; ib < 4; ++ib) {
    int pn = p ^ 1;
    if (ib < 3) {
#pragma unroll
      for (int t2 = 0; t2 < 4; ++t2)
        gl_lds16(abase + (size_t)((ib + 1) * 64 + t2 * 16) * 128, lA + pn * 8192 + t2 * 512);
    }
#pragma unroll
    for (int isub = 0; isub < 4; ++isub) {
      bf16x8 af[4];
#pragma unroll
      for (int kt = 0; kt < 4; ++kt)
        af[kt] = *(const bf16x8*)(fA + p * 8192 + kt * 2048 + isub * 512 + ((q ^ rsw) << 3));
#pragma unroll
      for (int js = 0; js < 8; ++js) {
        f32x4 s = {};
#pragma unroll
        for (int kt = 0; kt < 4; ++kt)
          s = mfma32(af[kt], bfr[js][kt], s);
        lacc[js] += (exp2fast(s[0]) + exp2fast(s[1])) + (exp2fast(s[2]) + exp2fast(s[3]));
      }
    }
    __syncthreads();
    p = pn;
  }
#pragma unroll
  for (int js = 0; js < 8; ++js) {
#pragma unroll
    for (int off = 16; off <= 32; off <<= 1)
      lacc[js] += __shfl_xor(lacc[js], off, 64);
  }
  if (l < 16) {
    float* lp = Lp + (size_t)ich * 65536 + (size_t)bh * TT + j0;
#pragma unroll
    for (int js = 0; js < 8; ++js) lp[js * 16 + l] = lacc[js];
  }
}

// ---------------- vscale: vvT[bh][d][j] *= rcp(sum_ich Lp[ich][j]) (in place) ----------------
__global__ __launch_bounds__(256) void vscale(const float* __restrict__ Lp,
                                              bf16_t* __restrict__ vvT) {
  int bh = blockIdx.x >> 3, jc = blockIdx.x & 7;
  int tid = threadIdx.x;
  int jj = jc * 256 + (tid & 63) * 4;
  int dg = tid >> 6;
  const float* lp = Lp + (size_t)bh * TT + jj;
  f32x4 a0 = *(const f32x4*)lp;
  f32x4 a1 = *(const f32x4*)(lp + 65536);
  f32x4 a2 = *(const f32x4*)(lp + 131072);
  f32x4 a3 = *(const f32x4*)(lp + 196608);
  f32x4 rl;
#pragma unroll
  for (int e = 0; e < 4; ++e)
    rl[e] = __builtin_amdgcn_rcpf((a0[e] + a1[e]) + (a2[e] + a3[e]));
  bf16_t* vb = vvT + ((size_t)bh * 64 + dg * 16) * TT + jj;
#pragma unroll
  for (int dd = 0; dd < 16; ++dd) {
    bf16x4 vv = *(const bf16x4*)(vb + (size_t)dd * TT);
    bf16x4 o;
#pragma unroll
    for (int e = 0; e < 4; ++e) o[e] = (bf16_t)((float)vv[e] * rl[e]);
    *(bf16x4*)(vb + (size_t)dd * TT) = o;
  }
}

// ---------------- K4: partial[i,d] over 256-j chunk; i-width 64/wave; bf16 partials ----------------
// grid 1024 = 8 xcd x (4 iblk x 4 bh' x 8 jch). dbuf, swizzled. V pre-normalized.
// NOTE: 256-thread blocks, launch_bounds(256,2) -> 96 arch VGPR + acc fits without spill.
// (512-thread/(512,4) variant spilled acc to scratch: 850 MB HBM traffic, 5x slower.)
__global__ __launch_bounds__(256, 2) void k4_attnv(const bf16_t* __restrict__ As,
                                                   const bf16_t* __restrict__ Bs,
                                                   const bf16_t* __restrict__ vvT,
                                                   bf16_t* __restrict__ Pp) {
  __shared__ union {
    struct { bf16_t Bt[2 * 8192]; bf16_t Vt[2 * 4096]; } m;
    float Tt[4][1088];
  } sm;
  int blk = blockIdx.x;
  int xcd = blk & 7, tb = blk >> 3;
  int iblk = tb & 3, pl = tb >> 2;       // pl: bh'(4) x jch(8)
  int bh = xcd * 4 + (pl >> 3), jch = pl & 7;
  int b = bh >> 4, h = bh & 15;
  int i0 = iblk * 256;
  int jbase = jch * 256;
  const int tid = threadIdx.x, w = tid >> 6, l = tid & 63;
  const int lm = l & 15, q = l >> 4;
  const int gg  = (l & 3) ^ ((l >> 3) & 3);
  const int rsw = (lm >> 1) & 3;
  const bf16_t* ar = As + (size_t)bh * CUR * 128 + (size_t)(i0 + w * 64 + lm) * 128 + q * 8;
  bf16x8 bi[4][4];
#pragma unroll
  for (int is = 0; is < 4; ++is)
#pragma unroll
    for (int kt = 0; kt < 4; ++kt)
      bi[is][kt] = *(const bf16x8*)(ar + is * 2048 + kt * 32);
  const bf16_t* bbase = Bs + ((size_t)bh * TT + jbase) * 128 + (size_t)(l >> 2) * 128 + w * 32 + gg * 8;
  int inst0 = w * 2, inst1 = w * 2 + 1;
  const bf16_t* vsrc0 = vvT + ((size_t)bh * 64 + (inst0 & 3) * 16 + (l >> 2)) * TT + jbase +
                        (inst0 >> 2) * 32 + gg * 8;
  const bf16_t* vsrc1 = vvT + ((size_t)bh * 64 + (inst1 & 3) * 16 + (l >> 2)) * TT + jbase +
                        (inst1 >> 2) * 32 + gg * 8;
  bf16_t* vdst0 = sm.m.Vt + (inst0 >> 2) * 2048 + (inst0 & 3) * 512;
  bf16_t* vdst1 = sm.m.Vt + (inst1 >> 2) * 2048 + (inst1 & 3) * 512;
  bf16_t* lB = sm.m.Bt + w * 2048;
  f32x4 acc[4][4] = {};
#pragma unroll
  for (int t2 = 0; t2 < 4; ++t2)
    gl_lds16(bbase + (size_t)t2 * 16 * 128, lB + t2 * 512);
  gl_lds16(vsrc0, vdst0);
  gl_lds16(vsrc1, vdst1);
  __syncthreads();
  int p = 0;
  for (int jb = 0; jb < 4; ++jb) {
    int pn = p ^ 1;
    if (jb < 3) {
      const bf16_t* bs2 = bbase + (size_t)(jb + 1) * 64 * 128;
#pragma unroll
      for (int t2 = 0; t2 < 4; ++t2)
        gl_lds16(bs2 + (size_t)t2 * 16 * 128, lB + pn * 8192 + t2 * 512);
      gl_lds16(vsrc0 + (jb + 1) * 64, vdst0 + pn * 4096);
      gl_lds16(vsrc1 + (jb + 1) * 64, vdst1 + pn * 4096);
    }
    const bf16_t* fB = sm.m.Bt + p * 8192 + lm * 32;
    const bf16_t* vf = sm.m.Vt + p * 4096 + lm * 32;
#pragma unroll
    for (int js = 0; js < 4; ++js) {
      bf16x8 af[4];
#pragma unroll
      for (int kt = 0; kt < 4; ++kt)
        af[kt] = *(const bf16x8*)(fB + kt * 2048 + js * 512 + ((q ^ rsw) << 3));
      f32x4 s[4] = {};
#pragma unroll
      for (int is = 0; is < 4; ++is)
#pragma unroll
        for (int kt = 0; kt < 4; ++kt)
          s[is] = mfma32(af[kt], bi[is][kt], s[is]);
      bf16x4 pp[4];
#pragma unroll
      for (int is = 0; is < 4; ++is)
#pragma unroll
        for (int e = 0; e < 4; ++e)
          pp[is][e] = (bf16_t)exp2fast(s[is][e]);
      int vg = ((js & 1) << 1) | (q >> 1);
      const bf16_t* vfa = vf + (js >> 1) * 2048 + ((vg ^ rsw) << 3) + ((q & 1) << 2);
#pragma unroll
      for (int dt = 0; dt < 4; ++dt) {
        bf16x4 a2 = *(const bf16x4*)(vfa + dt * 512);
#pragma unroll
        for (int is = 0; is < 4; ++is)
          acc[is][dt] = mfma16(a2, pp[is], acc[is][dt]);
      }
    }
    __syncthreads();
    p = pn;
  }
  // epilogue: per i-subtile transpose wT[64 d][16 i] -> rows, store bf16 partials
  float* Tw = sm.Tt[w];
  bf16_t* pout = Pp + ((size_t)jch << 21);
  int ir = l >> 2, dc = (l & 3) * 16;
#pragma unroll
  for (int is = 0; is < 4; ++is) {
#pragma unroll
    for (int dt = 0; dt < 4; ++dt) {
      f32x4 a = acc[is][dt];
#pragma unroll
      for (int r = 0; r < 4; ++r) Tw[(dt * 16 + q * 4 + r) * 17 + lm] = a[r];
    }
    __builtin_amdgcn_wave_barrier();
    int i = i0 + w * 64 + is * 16 + ir;
    bf16_t* orow = pout + ((size_t)(b * CUR + i)) * DM + h * 64 + dc;
#pragma unroll
    for (int e4 = 0; e4 < 4; ++e4) {
      bf16x4 o;
#pragma unroll
      for (int e = 0; e < 4; ++e) o[e] = (bf16_t)Tw[(dc + e4 * 4 + e) * 17 + ir];
      *(bf16x4*)(orow + e4 * 4) = o;
    }
    __builtin_amdgcn_wave_barrier();
  }
}

// ---------------- K4r: wbuf = bf16(sum of 8 bf16 partial chunks) ----------------
__global__ __launch_bounds__(256) void k4_reduce(const bf16_t* __restrict__ P,
                                                 bf16_t* __restrict__ wbuf) {
  int t = blockIdx.x * 256 + threadIdx.x;
  float s[4] = {0.f, 0.f, 0.f, 0.f};
#pragma unroll
  for (int c = 0; c < 8; ++c) {
    bf16x4 v = *(const bf16x4*)(P + ((size_t)c << 21) + (size_t)t * 4);
#pragma unroll
    for (int e = 0; e < 4; ++e) s[e] += (float)v[e];
  }
  bf16x4 o;
#pragma unroll
  for (int e = 0; e < 4; ++e) o[e] = (bf16_t)s[e];
  *(bf16x4*)(wbuf + (size_t)t * 4) = o;
}

// ---------------- K5: y = x + w @ Wfc^T + bfc (transposed epilogue) ----------------
__global__ __launch_bounds__(256) void k5_fc(const bf16_t* __restrict__ wb,
                                             const bf16_t* __restrict__ Wfcb,
                                             const float* __restrict__ x,
                                             const float* __restrict__ bfc,
                                             float* __restrict__ y) {
  __shared__ union { struct { bf16_t At[4096]; bf16_t Bt[8192]; } m; float Tt[4][272]; } sm;
  int blk = blockIdx.x;
  int r0 = (blk >> 3) * 64, c0 = (blk & 7) * 128;
  f32x4 acc[2][4] = {};
  gemm_core<2>(wb, Wfcb, r0, c0, sm.m.At, sm.m.Bt, acc);
  const int tid = threadIdx.x, w = tid >> 6, l = tid & 63;
  const int lm = l & 15, q = l >> 4;
  const int wrow = w >> 1, wcol = w & 1;
  float* Tw = sm.Tt[w];
#pragma unroll
  for (int it = 0; it < 2; ++it) {
#pragma unroll
    for (int jt = 0; jt < 4; ++jt) {
#pragma unroll
      for (int r = 0; r < 4; ++r) Tw[(q * 4 + r) * 17 + lm] = acc[it][jt][r];
      __builtin_amdgcn_wave_barrier();
      int row = r0 + wrow * 32 + it * 16 + lm;
      int cb = c0 + wcol * 64 + jt * 16 + q * 4;
      f32x4 xb4 = *(const f32x4*)(x + (size_t)row * DM + cb);
      f32x4 bf4 = *(const f32x4*)(bfc + cb);
      f32x4 o;
#pragma unroll
      for (int e = 0; e < 4; ++e) o[e] = Tw[lm * 17 + q * 4 + e] + xb4[e] + bf4[e];
      *(f32x4*)(y + (size_t)row * DM + cb) = o;
      __builtin_amdgcn_wave_barrier();
    }
  }
}

// ---------------- K6: LayerNorm ----------------
__global__ __launch_bounds__(256) void k6_ln(const float* __restrict__ y,
                                             const float* __restrict__ gamma,
                                             const float* __restrict__ beta,
                                             float* __restrict__ out) {
  int row = blockIdx.x, t = threadIdx.x;
  const float* yr = y + (size_t)row * DM;
  f32x4 v = *(const f32x4*)(yr + t * 4);
  float s = v[0] + v[1] + v[2] + v[3];
  float ss = v[0] * v[0] + v[1] * v[1] + v[2] * v[2] + v[3] * v[3];
#pragma unroll
  for (int off = 1; off < 64; off <<= 1) {
    s += __shfl_xor(s, off, 64);
    ss += __shfl_xor(ss, off, 64);
  }
  __shared__ float ps[4], pss[4];
  int wv = t >> 6, ln = t & 63;
  if (ln == 0) { ps[wv] = s; pss[wv] = ss; }
  __syncthreads();
  s = ps[0] + ps[1] + ps[2] + ps[3];
  ss = pss[0] + pss[1] + pss[2] + pss[3];
  float mu = s * (1.0f / DM);
  float var = ss * (1.0f / DM) - mu * mu;
  float rstd = rsqrtf(var + 1e-5f);
  f32x4 g = *(const f32x4*)(gamma + t * 4);
  f32x4 bb = *(const f32x4*)(beta + t * 4);
  f32x4 o;
#pragma unroll
  for (int e = 0; e < 4; ++e) o[e] = (v[e] - mu) * rstd * g[e] + bb[e];
  *(f32x4*)(out + (size_t)row * DM + t * 4) = o;
}

// ---------------- launch ----------------
extern "C" void kernel_launch(void* const* d_in, const int* in_sizes, int n_in,
                              void* d_out, int out_size, void* d_ws, size_t ws_size,
                              hipStream_t stream) {
  const float* x    = (const float*)d_in[0];
  const float* pos  = (const float*)d_in[1];
  const float* u    = (const float*)d_in[2];
  const float* v    = (const float*)d_in[3];
  const float* mem  = (const float*)d_in[5];
  const float* Wq   = (const float*)d_in[6];
  const float* Wkv  = (const float*)d_in[7];
  const float* Wfc  = (const float*)d_in[8];
  const float* bfc  = (const float*)d_in[9];
  const float* gam  = (const float*)d_in[10];
  const float* bet  = (const float*)d_in[11];
  float* out = (float*)d_out;

  char* ws = (char*)d_ws;
  const size_t MB = 1ull << 20;
  bf16_t* hb   = (bf16_t*)(ws);              // 0-8    (prep -> k12)
  bf16_t* wqb  = (bf16_t*)(ws + 8 * MB);     // 8-10   (prep -> k12)
  bf16_t* wkvb = (bf16_t*)(ws + 10 * MB);    // 10-14  (prep -> k12)
  bf16_t* As   = (bf16_t*)(ws + 14 * MB);    // 14-22  (k12 -> k4)
  bf16_t* Bs   = (bf16_t*)(ws + 22 * MB);    // 22-38  (prep/k12 -> k4)
  bf16_t* vvT  = (bf16_t*)(ws + 38 * MB);    // 38-46  (k12 -> vscale -> k4)
  bf16_t* wfcb = (bf16_t*)(ws + 46 * MB);    // 46-48  (prep -> k5)
  float*  Lp   = (float*) (ws + 48 * MB);    // 1 MB   (k3 -> vscale), 4 slices
  bf16_t* Pp   = (bf16_t*)(ws + 49 * MB);    // 49-81  (k4 -> k4r), 8 x 4 MB
  bf16_t* wbuf = (bf16_t*)(ws);              // 0-4    (k4r -> k5, hb dead)
  float*  y    = (float*) (ws + 4 * MB);     // 4-12   (k5 -> k6)

  prep_kernel<<<12288, 256, 0, stream>>>(Wq, Wkv, Wfc, mem, x, pos,
                                         wqb, wkvb, wfcb, hb, Bs);
  k12_gemm<<<768, 256, 0, stream>>>(hb, wqb, wkvb, u, v, As, Bs, vvT);

  k3_stats<<<512, 256, 0, stream>>>(As, Bs, Lp);
  vscale<<<256, 256, 0, stream>>>(Lp, vvT);
  k4_attnv<<<1024, 256, 0, stream>>>(As, Bs, vvT, Pp);
  k4_reduce<<<2048, 256, 0, stream>>>(Pp, wbuf);

  k5_fc<<<256, 256, 0, stream>>>(wbuf, wfcb, x, bfc, y);
  k6_ln<<<2048, 256, 0, stream>>>(y, gam, bet, out);
}